// Round 1
// baseline (3520.210 us; speedup 1.0000x reference)
//
#include <hip/hip_runtime.h>
#include <hip/hip_bf16.h>

#define DD    1024
#define NROWS 3072
#define NLAY  17
#define MS    20     // LDS stride for 16x16 matrices

// ---------------------------------------------------------------- prep
// Build X0 rows from input: ch0/ch1 copy, ch2 = transpose of (16,64) -> (64,16)
__global__ __launch_bounds__(256) void prep_kernel(const float* __restrict__ Xin,
                                                   float* __restrict__ X) {
  const int row = blockIdx.x;           // 0..3071  (= b*3 + c)
  const int c   = row % 3;
  const float* src = Xin + (size_t)row * DD;
  float* dst = X + (size_t)row * DD;
  for (int t = threadIdx.x; t < DD; t += 256) {
    float v;
    if (c == 2) {
      const int i = t >> 4, j = t & 15;   // dst[i*16+j] = src[j*64+i]
      v = src[j * 64 + i];
    } else {
      v = src[t];
    }
    dst[t] = v;
  }
}

// ---------------------------------------------------------------- GEMM
// Y[m][e] = sum_d A[m][d] * W[e][d]   (+ optional residual/bias/relu fuse)
// fuse==1: Y = A + h * relu(dot + bias)
__global__ __launch_bounds__(256) void gemm_kernel(
    const float* __restrict__ A, const float* __restrict__ W,
    const float* __restrict__ bias, const float* __restrict__ hp,
    float* __restrict__ Y, int fuse)
{
  __shared__ float As[8 * 132];
  __shared__ float Bs[8 * 132];
  const int tid = threadIdx.x;
  const int bm = blockIdx.y * 128;
  const int bn = blockIdx.x * 128;
  const int tm = (tid >> 4) << 3;     // 0..120
  const int tn = (tid & 15) << 3;     // 0..120
  const int lr = tid >> 1;            // 0..127
  const int lk = (tid & 1) << 2;      // 0 or 4
  const float* Ap = A + (size_t)(bm + lr) * DD + lk;
  const float* Wp = W + (size_t)(bn + lr) * DD + lk;
  float acc[8][8] = {};

  for (int k0 = 0; k0 < DD; k0 += 8) {
    const float4 a4 = *(const float4*)(Ap + k0);
    const float4 b4 = *(const float4*)(Wp + k0);
    __syncthreads();   // previous tile's compute done before overwrite
    As[(lk + 0) * 132 + lr] = a4.x;
    As[(lk + 1) * 132 + lr] = a4.y;
    As[(lk + 2) * 132 + lr] = a4.z;
    As[(lk + 3) * 132 + lr] = a4.w;
    Bs[(lk + 0) * 132 + lr] = b4.x;
    Bs[(lk + 1) * 132 + lr] = b4.y;
    Bs[(lk + 2) * 132 + lr] = b4.z;
    Bs[(lk + 3) * 132 + lr] = b4.w;
    __syncthreads();
#pragma unroll
    for (int k = 0; k < 8; ++k) {
      float a[8], b[8];
      *(float4*)&a[0] = *(const float4*)&As[k * 132 + tm];
      *(float4*)&a[4] = *(const float4*)&As[k * 132 + tm + 4];
      *(float4*)&b[0] = *(const float4*)&Bs[k * 132 + tn];
      *(float4*)&b[4] = *(const float4*)&Bs[k * 132 + tn + 4];
#pragma unroll
      for (int i = 0; i < 8; ++i)
#pragma unroll
        for (int j = 0; j < 8; ++j)
          acc[i][j] = fmaf(a[i], b[j], acc[i][j]);
    }
  }

  const float h = fuse ? hp[0] : 0.0f;
  for (int i = 0; i < 8; ++i) {
    const int m = bm + tm + i;
    float* yr = Y + (size_t)m * DD + bn + tn;
    const float* ar = A + (size_t)m * DD + bn + tn;
#pragma unroll
    for (int j0 = 0; j0 < 8; j0 += 4) {
      float4 d;
      d.x = acc[i][j0 + 0]; d.y = acc[i][j0 + 1];
      d.z = acc[i][j0 + 2]; d.w = acc[i][j0 + 3];
      if (fuse) {
        const int n = bn + tn + j0;
        const float4 xv = *(const float4*)(ar + j0);
        const float4 bv = *(const float4*)(bias + n);
        d.x = xv.x + h * fmaxf(d.x + bv.x, 0.0f);
        d.y = xv.y + h * fmaxf(d.y + bv.y, 0.0f);
        d.z = xv.z + h * fmaxf(d.z + bv.z, 0.0f);
        d.w = xv.w + h * fmaxf(d.w + bv.w, 0.0f);
      }
      *(float4*)(yr + j0) = d;
    }
  }
}

// ---------------------------------------------------------------- projection
// Blocks 0..511: 4 waves x 1 polar projection each (channels 0/2 rows).
// Blocks 512..767: channel-1 passthrough copy (Y -> X, + bf16 stage).
// polar(A) = A * (A^T A)^{-1/2}; Newton-Schulz coupled iteration on G/|A|_F^2.
__global__ __launch_bounds__(256) void proj_kernel(
    const float* __restrict__ Yg, float* __restrict__ Xg,
    __hip_bfloat16* __restrict__ stage, int layer, int iters)
{
  __shared__ float At[4][16 * 68];
  __shared__ float Mb[4][5][16 * MS];

  const int wave = threadIdx.x >> 6;
  const int lane = threadIdx.x & 63;

  if (blockIdx.x >= 512) {                       // ---- channel-1 copy path
    const int b = (blockIdx.x - 512) * 4 + wave; // 0..1023
    const int row = b * 3 + 1;
    const float* src = Yg + (size_t)row * DD + lane * 16;
    float* dst = Xg + (size_t)row * DD + lane * 16;
    float v[16];
#pragma unroll
    for (int q = 0; q < 4; ++q) {
      const float4 t4 = *(const float4*)(src + q * 4);
      v[q*4+0]=t4.x; v[q*4+1]=t4.y; v[q*4+2]=t4.z; v[q*4+3]=t4.w;
      *(float4*)(dst + q * 4) = t4;
    }
    union { __hip_bfloat16 hh[16]; uint4 u[2]; } pk;
#pragma unroll
    for (int j = 0; j < 16; ++j) pk.hh[j] = __float2bfloat16(v[j]);
    uint4* sd = (uint4*)(stage + ((size_t)layer * NROWS + row) * DD + lane * 16);
    sd[0] = pk.u[0]; sd[1] = pk.u[1];
    return;
  }

  const int p = blockIdx.x * 4 + wave;   // 0..2047
  const int b = p >> 1;
  const int row = b * 3 + (p & 1) * 2;   // channel 0 or 2
  const float* src = Yg + (size_t)row * DD + lane * 16;

  // lane = row i of A(64x16); v = A[i][0..15]
  float v[16];
#pragma unroll
  for (int q = 0; q < 4; ++q) {
    const float4 t4 = *(const float4*)(src + q * 4);
    v[q*4+0]=t4.x; v[q*4+1]=t4.y; v[q*4+2]=t4.z; v[q*4+3]=t4.w;
  }
  float f2 = 0.f;
#pragma unroll
  for (int j = 0; j < 16; ++j) f2 += v[j] * v[j];
#pragma unroll
  for (int o = 32; o > 0; o >>= 1) f2 += __shfl_xor(f2, o, 64);
  const float s = rsqrtf(f2 + 1e-30f);
#pragma unroll
  for (int j = 0; j < 16; ++j) v[j] *= s;       // v = scaled A row

  float* at = At[wave];                          // A^T, [16][68]
#pragma unroll
  for (int j = 0; j < 16; ++j) at[j * 68 + lane] = v[j];
  __syncthreads();

  const int r  = lane >> 2;          // my output row  (0..15)
  const int c0 = (lane & 3) * 4;     // my 4-col block
  // G[r][c0..c0+3] = (sA)^T (sA)
  float g[4] = {0,0,0,0};
  for (int i0 = 0; i0 < 64; i0 += 4) {
    const float4 aj = *(const float4*)&at[r * 68 + i0];
#pragma unroll
    for (int kk = 0; kk < 4; ++kk) {
      const float4 ak = *(const float4*)&at[(c0 + kk) * 68 + i0];
      g[kk] += aj.x*ak.x + aj.y*ak.y + aj.z*ak.z + aj.w*ak.w;
    }
  }
  float* Yb  = Mb[wave][0];
  float* Yb2 = Mb[wave][1];
  float* Zb  = Mb[wave][2];
  float* Zb2 = Mb[wave][3];
  float* Tb  = Mb[wave][4];
  *(float4*)&Yb[r * MS + c0] = make_float4(g[0], g[1], g[2], g[3]);
  Zb[r*MS+c0+0] = (r == c0+0) ? 1.f : 0.f;
  Zb[r*MS+c0+1] = (r == c0+1) ? 1.f : 0.f;
  Zb[r*MS+c0+2] = (r == c0+2) ? 1.f : 0.f;
  Zb[r*MS+c0+3] = (r == c0+3) ? 1.f : 0.f;
  __syncthreads();

  for (int it = 0; it < iters; ++it) {
    // T = 0.5*(3I - Z*Y)
    float p0=0,p1=0,p2=0,p3=0;
#pragma unroll
    for (int k = 0; k < 16; ++k) {
      const float zk = Zb[r * MS + k];
      const float4 y4 = *(const float4*)&Yb[k * MS + c0];
      p0 = fmaf(zk, y4.x, p0); p1 = fmaf(zk, y4.y, p1);
      p2 = fmaf(zk, y4.z, p2); p3 = fmaf(zk, y4.w, p3);
    }
    float4 tv;
    tv.x = 0.5f * ((r == c0+0 ? 3.f : 0.f) - p0);
    tv.y = 0.5f * ((r == c0+1 ? 3.f : 0.f) - p1);
    tv.z = 0.5f * ((r == c0+2 ? 3.f : 0.f) - p2);
    tv.w = 0.5f * ((r == c0+3 ? 3.f : 0.f) - p3);
    *(float4*)&Tb[r * MS + c0] = tv;
    __syncthreads();
    // Ynew = Y*T ; Znew = T*Z
    float4 py = make_float4(0,0,0,0), pz = make_float4(0,0,0,0);
#pragma unroll
    for (int k = 0; k < 16; ++k) {
      const float yk = Yb[r * MS + k];
      const float4 t4 = *(const float4*)&Tb[k * MS + c0];
      py.x = fmaf(yk, t4.x, py.x); py.y = fmaf(yk, t4.y, py.y);
      py.z = fmaf(yk, t4.z, py.z); py.w = fmaf(yk, t4.w, py.w);
      const float tk = Tb[r * MS + k];
      const float4 z4 = *(const float4*)&Zb[k * MS + c0];
      pz.x = fmaf(tk, z4.x, pz.x); pz.y = fmaf(tk, z4.y, pz.y);
      pz.z = fmaf(tk, z4.z, pz.z); pz.w = fmaf(tk, z4.w, pz.w);
    }
    *(float4*)&Yb2[r * MS + c0] = py;
    *(float4*)&Zb2[r * MS + c0] = pz;
    __syncthreads();
    float* t;
    t = Yb; Yb = Yb2; Yb2 = t;
    t = Zb; Zb = Zb2; Zb2 = t;
  }

  // Up[i][j] = sum_k (sA)[i][k] * Z[k][j]   (lane = row i)
  float up[16] = {};
#pragma unroll
  for (int k = 0; k < 16; ++k) {
    const float a = v[k];
#pragma unroll
    for (int j0 = 0; j0 < 16; j0 += 4) {
      const float4 z4 = *(const float4*)&Zb[k * MS + j0];  // uniform -> broadcast
      up[j0+0] = fmaf(a, z4.x, up[j0+0]);
      up[j0+1] = fmaf(a, z4.y, up[j0+1]);
      up[j0+2] = fmaf(a, z4.z, up[j0+2]);
      up[j0+3] = fmaf(a, z4.w, up[j0+3]);
    }
  }
  float* dst = Xg + (size_t)row * DD + lane * 16;
#pragma unroll
  for (int q = 0; q < 4; ++q)
    *(float4*)(dst + q*4) = make_float4(up[q*4], up[q*4+1], up[q*4+2], up[q*4+3]);
  union { __hip_bfloat16 hh[16]; uint4 u[2]; } pk;
#pragma unroll
  for (int j = 0; j < 16; ++j) pk.hh[j] = __float2bfloat16(up[j]);
  uint4* sd = (uint4*)(stage + ((size_t)layer * NROWS + row) * DD + lane * 16);
  sd[0] = pk.u[0]; sd[1] = pk.u[1];
}

// ---------------------------------------------------------------- transpose epilogue
// stage (l, row, d) bf16 -> out (row, d, l) fp32, coalesced both ways via LDS
__global__ __launch_bounds__(256) void transpose_kernel(
    const __hip_bfloat16* __restrict__ stage, float* __restrict__ outT)
{
  __shared__ float buf[256 * 18];
  const int row = blockIdx.y;          // 0..3071
  const int d0  = blockIdx.x * 256;    // 0,256,512,768
  const int t   = threadIdx.x;
  for (int l = 0; l < NLAY; ++l)
    buf[t * 18 + l] = __bfloat162float(stage[((size_t)l * NROWS + row) * DD + d0 + t]);
  __syncthreads();
  const size_t ob = (size_t)(row * DD + d0) * NLAY;
  for (int i = 0; i < NLAY; ++i) {
    const int idx = i * 256 + t;       // < 4352
    const int dd = idx / 17, ll = idx % 17;
    outT[ob + idx] = buf[dd * 18 + ll];
  }
}

// ---------------------------------------------------------------- classify
// Z = U @ S[:16,:16] @ V^T (64x64); logits = Z @ Wc^T + bc; softmax
__global__ __launch_bounds__(256) void classify_kernel(
    const float* __restrict__ X, const float* __restrict__ Wc,
    const float* __restrict__ bc, float* __restrict__ out)
{
  __shared__ float U[64*17], S[16*17], V[64*17], T[64*17];
  __shared__ float Z[4096];
  __shared__ float red[256];
  __shared__ float logits[16];
  const int b = blockIdx.x, t = threadIdx.x;
  const float* x0 = X + (size_t)(b*3+0) * DD;
  const float* x1 = X + (size_t)(b*3+1) * DD;
  const float* x2 = X + (size_t)(b*3+2) * DD;
  for (int e = t; e < 1024; e += 256) {
    const int i = e >> 4, j = e & 15;
    U[i*17+j] = x0[e];
    V[i*17+j] = x2[e];
  }
  { const int i = t >> 4, j = t & 15; if (t < 256) S[i*17+j] = x1[i*16+j]; }
  __syncthreads();
  for (int e = t; e < 1024; e += 256) {     // T = U @ S
    const int i = e >> 4, j = e & 15;
    float a = 0.f;
    for (int k = 0; k < 16; ++k) a = fmaf(U[i*17+k], S[k*17+j], a);
    T[i*17+j] = a;
  }
  __syncthreads();
  for (int e = t; e < 4096; e += 256) {     // Z = T @ V^T
    const int i = e >> 6, j = e & 63;
    float a = 0.f;
    for (int k = 0; k < 16; ++k) a = fmaf(T[i*17+k], V[j*17+k], a);
    Z[e] = a;
  }
  __syncthreads();
  for (int n = 0; n < 10; ++n) {
    float part = 0.f;
    const float* wr = Wc + (size_t)n * 4096;
    for (int e = t; e < 4096; e += 256) part = fmaf(Z[e], wr[e], part);
    red[t] = part; __syncthreads();
    for (int off = 128; off > 0; off >>= 1) {
      if (t < off) red[t] += red[t + off];
      __syncthreads();
    }
    if (t == 0) logits[n] = red[0] + bc[n];
    __syncthreads();
  }
  if (t == 0) {
    float mx = logits[0];
    for (int n = 1; n < 10; ++n) mx = fmaxf(mx, logits[n]);
    float ex[10], sm = 0.f;
    for (int n = 0; n < 10; ++n) { ex[n] = expf(logits[n] - mx); sm += ex[n]; }
    const float inv = 1.f / sm;
    for (int n = 0; n < 10; ++n) {
      out[b*10 + n] = ex[n] * inv;          // X_predicted
      out[10240 + b*10 + n] = logits[n];    // X_classified
    }
  }
}

// ---------------------------------------------------------------- launch
extern "C" void kernel_launch(void* const* d_in, const int* in_sizes, int n_in,
                              void* d_out, int out_size, void* d_ws, size_t ws_size,
                              hipStream_t stream) {
  const float* Xin = (const float*)d_in[0];
  const float* hp  = (const float*)d_in[1];
  const float* W0  = (const float*)d_in[2];
  const float* Ws  = (const float*)d_in[3];
  const float* bs  = (const float*)d_in[4];
  const float* Wc  = (const float*)d_in[5];
  const float* bc  = (const float*)d_in[6];
  float* out = (float*)d_out;

  char* ws = (char*)d_ws;
  float* Xb = (float*)ws;                                   // 3072*1024 f32
  float* Yb = Xb + (size_t)NROWS * DD;                      // 3072*1024 f32
  __hip_bfloat16* stage =
      (__hip_bfloat16*)(ws + 2 * (size_t)NROWS * DD * 4);   // 17*3072*1024 bf16

  prep_kernel<<<NROWS, 256, 0, stream>>>(Xin, Xb);

  // layer 0: Linear (no bias), then projection
  gemm_kernel<<<dim3(8, 24), 256, 0, stream>>>(Xb, W0, nullptr, nullptr, Yb, 0);
  proj_kernel<<<768, 256, 0, stream>>>(Yb, Xb, stage, 0, 16);

  for (int l = 0; l < 16; ++l) {
    gemm_kernel<<<dim3(8, 24), 256, 0, stream>>>(
        Xb, Ws + (size_t)l * DD * DD, bs + (size_t)l * DD, hp, Yb, 1);
    proj_kernel<<<768, 256, 0, stream>>>(Yb, Xb, stage, l + 1, 12);
  }

  transpose_kernel<<<dim3(4, NROWS), 256, 0, stream>>>(stage, out + 20480);
  classify_kernel<<<1024, 256, 0, stream>>>(Xb, Wc, bc, out);
}

// Round 2
// 1466.463 us; speedup vs baseline: 2.4005x; 2.4005x over previous
//
#include <hip/hip_runtime.h>
#include <hip/hip_bf16.h>

#define DD    1024
#define NROWS 3072
#define NLAY  17
#define MS    20     // LDS stride for 16x16 matrices

typedef __attribute__((ext_vector_type(8))) short short8;
typedef __attribute__((ext_vector_type(4))) float floatx4;

// ---------------------------------------------------------------- weight convert
// W0 (1M) ++ Ws (16M) fp32 -> bf16, 4 elems/thread
__global__ __launch_bounds__(256) void convw_kernel(const float* __restrict__ W0,
                                                    const float* __restrict__ Ws,
                                                    ushort* __restrict__ Wbf) {
  const size_t i4 = ((size_t)blockIdx.x * 256 + threadIdx.x) * 4;
  float4 v;
  if (i4 < 1048576) v = *(const float4*)(W0 + i4);
  else              v = *(const float4*)(Ws + (i4 - 1048576));
  union { __hip_bfloat16 h[4]; ushort u[4]; } pk;
  pk.h[0] = __float2bfloat16(v.x); pk.h[1] = __float2bfloat16(v.y);
  pk.h[2] = __float2bfloat16(v.z); pk.h[3] = __float2bfloat16(v.w);
  *(ushort4*)(Wbf + i4) = *(ushort4*)pk.u;
}

// ---------------------------------------------------------------- prep
// Build X0 rows (bf16): ch0/ch1 copy, ch2 = transpose of (16,64) -> (64,16)
__global__ __launch_bounds__(256) void prep_kernel(const float* __restrict__ Xin,
                                                   ushort* __restrict__ X0bf) {
  const int row = blockIdx.x;           // 0..3071  (= b*3 + c)
  const int c   = row % 3;
  const float* src = Xin + (size_t)row * DD;
  ushort* dst = X0bf + (size_t)row * DD;
  for (int t = threadIdx.x; t < DD; t += 256) {
    float v;
    if (c == 2) v = src[(t & 15) * 64 + (t >> 4)];
    else        v = src[t];
    __hip_bfloat16 h = __float2bfloat16(v);
    dst[t] = *(ushort*)&h;
  }
}

// ---------------------------------------------------------------- MFMA GEMM
// Y[m][e] = sum_d A[m][d] * W[e][d]   (A,W bf16 row-major, NT)
// fuse==1: Y = Xres + h * relu(dot + bias)   (Xres fp32)
// 128x128 tile, BK=32, 4 waves 2x2, each wave 4x4 mfma_f32_16x16x32_bf16
__global__ __launch_bounds__(256) void gemm_kernel(
    const ushort* __restrict__ Abf, const ushort* __restrict__ Wbf,
    const float* __restrict__ Xres, const float* __restrict__ bias,
    const float* __restrict__ hp, float* __restrict__ Y, int fuse)
{
  __shared__ __align__(16) ushort As[128 * 32];
  __shared__ __align__(16) ushort Bs[128 * 32];
  const int tid  = threadIdx.x;
  const int wave = tid >> 6, lane = tid & 63;
  const int bm = blockIdx.y * 128, bn = blockIdx.x * 128;

  // staging: wave w covers rows [q*64 + w*16, +16), lane -> (row=lane>>2, 16B col chunk=lane&3)
  const int srow = wave * 16 + (lane >> 2);
  const int scol = (lane & 3) * 8;                  // bf16 elements
  const ushort* ga0 = Abf + (size_t)(bm + srow) * DD + scol;
  const ushort* gb0 = Wbf + (size_t)(bn + srow) * DD + scol;

  const int wm0 = (wave >> 1) * 64, wn0 = (wave & 1) * 64;
  const int m = lane & 15, quad = lane >> 4;

  floatx4 acc[4][4] = {};

  for (int k0 = 0; k0 < DD; k0 += 32) {
    __syncthreads();                                // prev tile's reads done
#pragma unroll
    for (int q = 0; q < 2; ++q) {
      __builtin_amdgcn_global_load_lds(
          (const __attribute__((address_space(1))) unsigned int*)(ga0 + (size_t)q * 64 * DD + k0),
          (__attribute__((address_space(3))) unsigned int*)&As[(q * 64 + wave * 16) * 32],
          16, 0, 0);
      __builtin_amdgcn_global_load_lds(
          (const __attribute__((address_space(1))) unsigned int*)(gb0 + (size_t)q * 64 * DD + k0),
          (__attribute__((address_space(3))) unsigned int*)&Bs[(q * 64 + wave * 16) * 32],
          16, 0, 0);
    }
    __syncthreads();                                // staging visible

    short8 av[4], bv[4];
#pragma unroll
    for (int i = 0; i < 4; ++i)
      av[i] = *(const short8*)&As[(wm0 + i * 16 + m) * 32 + quad * 8];
#pragma unroll
    for (int j = 0; j < 4; ++j)
      bv[j] = *(const short8*)&Bs[(wn0 + j * 16 + m) * 32 + quad * 8];
#pragma unroll
    for (int i = 0; i < 4; ++i)
#pragma unroll
      for (int j = 0; j < 4; ++j)
        acc[i][j] = __builtin_amdgcn_mfma_f32_16x16x32_bf16(av[i], bv[j], acc[i][j], 0, 0, 0);
  }

  // epilogue: C layout col=lane&15, row=quad*4+reg
  const float h = fuse ? hp[0] : 0.0f;
#pragma unroll
  for (int i = 0; i < 4; ++i) {
#pragma unroll
    for (int r = 0; r < 4; ++r) {
      const int grow = bm + wm0 + i * 16 + quad * 4 + r;
      float* yr = Y + (size_t)grow * DD;
      const float* xr = Xres + (size_t)grow * DD;
#pragma unroll
      for (int j = 0; j < 4; ++j) {
        const int gcol = bn + wn0 + j * 16 + m;
        float d = acc[i][j][r];
        if (fuse) d = xr[gcol] + h * fmaxf(d + bias[gcol], 0.0f);
        yr[gcol] = d;
      }
    }
  }
}

// ---------------------------------------------------------------- projection
// Blocks 0..511: 4 waves x 1 polar projection each (channels 0/2 rows).
// Blocks 512..767: channel-1 passthrough copy (Y -> X, + bf16 stage).
// polar(A) = A * (A^T A)^{-1/2}; Newton-Schulz coupled iteration on G/|A|_F^2.
__global__ __launch_bounds__(256) void proj_kernel(
    const float* __restrict__ Yg, float* __restrict__ Xg,
    __hip_bfloat16* __restrict__ stage, int layer, int iters)
{
  __shared__ float At[4][16 * 68];
  __shared__ float Mb[4][5][16 * MS];

  const int wave = threadIdx.x >> 6;
  const int lane = threadIdx.x & 63;

  if (blockIdx.x >= 512) {                       // ---- channel-1 copy path
    const int b = (blockIdx.x - 512) * 4 + wave; // 0..1023
    const int row = b * 3 + 1;
    const float* src = Yg + (size_t)row * DD + lane * 16;
    float* dst = Xg + (size_t)row * DD + lane * 16;
    float v[16];
#pragma unroll
    for (int q = 0; q < 4; ++q) {
      const float4 t4 = *(const float4*)(src + q * 4);
      v[q*4+0]=t4.x; v[q*4+1]=t4.y; v[q*4+2]=t4.z; v[q*4+3]=t4.w;
      *(float4*)(dst + q * 4) = t4;
    }
    union { __hip_bfloat16 hh[16]; uint4 u[2]; } pk;
#pragma unroll
    for (int j = 0; j < 16; ++j) pk.hh[j] = __float2bfloat16(v[j]);
    uint4* sd = (uint4*)(stage + ((size_t)layer * NROWS + row) * DD + lane * 16);
    sd[0] = pk.u[0]; sd[1] = pk.u[1];
    return;
  }

  const int p = blockIdx.x * 4 + wave;   // 0..2047
  const int b = p >> 1;
  const int row = b * 3 + (p & 1) * 2;   // channel 0 or 2
  const float* src = Yg + (size_t)row * DD + lane * 16;

  // lane = row i of A(64x16); v = A[i][0..15]
  float v[16];
#pragma unroll
  for (int q = 0; q < 4; ++q) {
    const float4 t4 = *(const float4*)(src + q * 4);
    v[q*4+0]=t4.x; v[q*4+1]=t4.y; v[q*4+2]=t4.z; v[q*4+3]=t4.w;
  }
  float f2 = 0.f;
#pragma unroll
  for (int j = 0; j < 16; ++j) f2 += v[j] * v[j];
#pragma unroll
  for (int o = 32; o > 0; o >>= 1) f2 += __shfl_xor(f2, o, 64);
  const float s = rsqrtf(f2 + 1e-30f);
#pragma unroll
  for (int j = 0; j < 16; ++j) v[j] *= s;       // v = scaled A row

  float* at = At[wave];                          // A^T, [16][68]
#pragma unroll
  for (int j = 0; j < 16; ++j) at[j * 68 + lane] = v[j];
  __syncthreads();

  const int r  = lane >> 2;          // my output row  (0..15)
  const int c0 = (lane & 3) * 4;     // my 4-col block
  // G[r][c0..c0+3] = (sA)^T (sA)
  float g[4] = {0,0,0,0};
  for (int i0 = 0; i0 < 64; i0 += 4) {
    const float4 aj = *(const float4*)&at[r * 68 + i0];
#pragma unroll
    for (int kk = 0; kk < 4; ++kk) {
      const float4 ak = *(const float4*)&at[(c0 + kk) * 68 + i0];
      g[kk] += aj.x*ak.x + aj.y*ak.y + aj.z*ak.z + aj.w*ak.w;
    }
  }
  float* Yb  = Mb[wave][0];
  float* Yb2 = Mb[wave][1];
  float* Zb  = Mb[wave][2];
  float* Zb2 = Mb[wave][3];
  float* Tb  = Mb[wave][4];
  *(float4*)&Yb[r * MS + c0] = make_float4(g[0], g[1], g[2], g[3]);
  Zb[r*MS+c0+0] = (r == c0+0) ? 1.f : 0.f;
  Zb[r*MS+c0+1] = (r == c0+1) ? 1.f : 0.f;
  Zb[r*MS+c0+2] = (r == c0+2) ? 1.f : 0.f;
  Zb[r*MS+c0+3] = (r == c0+3) ? 1.f : 0.f;
  __syncthreads();

  for (int it = 0; it < iters; ++it) {
    // T = 0.5*(3I - Z*Y)
    float p0=0,p1=0,p2=0,p3=0;
#pragma unroll
    for (int k = 0; k < 16; ++k) {
      const float zk = Zb[r * MS + k];
      const float4 y4 = *(const float4*)&Yb[k * MS + c0];
      p0 = fmaf(zk, y4.x, p0); p1 = fmaf(zk, y4.y, p1);
      p2 = fmaf(zk, y4.z, p2); p3 = fmaf(zk, y4.w, p3);
    }
    float4 tv;
    tv.x = 0.5f * ((r == c0+0 ? 3.f : 0.f) - p0);
    tv.y = 0.5f * ((r == c0+1 ? 3.f : 0.f) - p1);
    tv.z = 0.5f * ((r == c0+2 ? 3.f : 0.f) - p2);
    tv.w = 0.5f * ((r == c0+3 ? 3.f : 0.f) - p3);
    *(float4*)&Tb[r * MS + c0] = tv;
    __syncthreads();
    // Ynew = Y*T ; Znew = T*Z
    float4 py = make_float4(0,0,0,0), pz = make_float4(0,0,0,0);
#pragma unroll
    for (int k = 0; k < 16; ++k) {
      const float yk = Yb[r * MS + k];
      const float4 t4 = *(const float4*)&Tb[k * MS + c0];
      py.x = fmaf(yk, t4.x, py.x); py.y = fmaf(yk, t4.y, py.y);
      py.z = fmaf(yk, t4.z, py.z); py.w = fmaf(yk, t4.w, py.w);
      const float tk = Tb[r * MS + k];
      const float4 z4 = *(const float4*)&Zb[k * MS + c0];
      pz.x = fmaf(tk, z4.x, pz.x); pz.y = fmaf(tk, z4.y, pz.y);
      pz.z = fmaf(tk, z4.z, pz.z); pz.w = fmaf(tk, z4.w, pz.w);
    }
    *(float4*)&Yb2[r * MS + c0] = py;
    *(float4*)&Zb2[r * MS + c0] = pz;
    __syncthreads();
    float* t;
    t = Yb; Yb = Yb2; Yb2 = t;
    t = Zb; Zb = Zb2; Zb2 = t;
  }

  // Up[i][j] = sum_k (sA)[i][k] * Z[k][j]   (lane = row i)
  float up[16] = {};
#pragma unroll
  for (int k = 0; k < 16; ++k) {
    const float a = v[k];
#pragma unroll
    for (int j0 = 0; j0 < 16; j0 += 4) {
      const float4 z4 = *(const float4*)&Zb[k * MS + j0];  // uniform -> broadcast
      up[j0+0] = fmaf(a, z4.x, up[j0+0]);
      up[j0+1] = fmaf(a, z4.y, up[j0+1]);
      up[j0+2] = fmaf(a, z4.z, up[j0+2]);
      up[j0+3] = fmaf(a, z4.w, up[j0+3]);
    }
  }
  float* dst = Xg + (size_t)row * DD + lane * 16;
#pragma unroll
  for (int q = 0; q < 4; ++q)
    *(float4*)(dst + q*4) = make_float4(up[q*4], up[q*4+1], up[q*4+2], up[q*4+3]);
  union { __hip_bfloat16 hh[16]; uint4 u[2]; } pk;
#pragma unroll
  for (int j = 0; j < 16; ++j) pk.hh[j] = __float2bfloat16(up[j]);
  uint4* sd = (uint4*)(stage + ((size_t)layer * NROWS + row) * DD + lane * 16);
  sd[0] = pk.u[0]; sd[1] = pk.u[1];
}

// ---------------------------------------------------------------- transpose epilogue
// stage (l, row, d) bf16 -> out (row, d, l) fp32, coalesced both ways via LDS
__global__ __launch_bounds__(256) void transpose_kernel(
    const __hip_bfloat16* __restrict__ stage, float* __restrict__ outT)
{
  __shared__ float buf[256 * 18];
  const int row = blockIdx.y;          // 0..3071
  const int d0  = blockIdx.x * 256;    // 0,256,512,768
  const int t   = threadIdx.x;
  for (int l = 0; l < NLAY; ++l)
    buf[t * 18 + l] = __bfloat162float(stage[((size_t)l * NROWS + row) * DD + d0 + t]);
  __syncthreads();
  const size_t ob = (size_t)(row * DD + d0) * NLAY;
  for (int i = 0; i < NLAY; ++i) {
    const int idx = i * 256 + t;       // < 4352
    const int dd = idx / 17, ll = idx % 17;
    outT[ob + idx] = buf[dd * 18 + ll];
  }
}

// ---------------------------------------------------------------- classify
// Z = U @ S[:16,:16] @ V^T (64x64); logits = Z @ Wc^T + bc; softmax
__global__ __launch_bounds__(256) void classify_kernel(
    const float* __restrict__ X, const float* __restrict__ Wc,
    const float* __restrict__ bc, float* __restrict__ out)
{
  __shared__ float U[64*17], S[16*17], V[64*17], T[64*17];
  __shared__ float Z[4096];
  __shared__ float red[256];
  __shared__ float logits[16];
  const int b = blockIdx.x, t = threadIdx.x;
  const float* x0 = X + (size_t)(b*3+0) * DD;
  const float* x1 = X + (size_t)(b*3+1) * DD;
  const float* x2 = X + (size_t)(b*3+2) * DD;
  for (int e = t; e < 1024; e += 256) {
    const int i = e >> 4, j = e & 15;
    U[i*17+j] = x0[e];
    V[i*17+j] = x2[e];
  }
  { const int i = t >> 4, j = t & 15; if (t < 256) S[i*17+j] = x1[i*16+j]; }
  __syncthreads();
  for (int e = t; e < 1024; e += 256) {     // T = U @ S
    const int i = e >> 4, j = e & 15;
    float a = 0.f;
    for (int k = 0; k < 16; ++k) a = fmaf(U[i*17+k], S[k*17+j], a);
    T[i*17+j] = a;
  }
  __syncthreads();
  for (int e = t; e < 4096; e += 256) {     // Z = T @ V^T
    const int i = e >> 6, j = e & 63;
    float a = 0.f;
    for (int k = 0; k < 16; ++k) a = fmaf(T[i*17+k], V[j*17+k], a);
    Z[e] = a;
  }
  __syncthreads();
  for (int n = 0; n < 10; ++n) {
    float part = 0.f;
    const float* wr = Wc + (size_t)n * 4096;
    for (int e = t; e < 4096; e += 256) part = fmaf(Z[e], wr[e], part);
    red[t] = part; __syncthreads();
    for (int off = 128; off > 0; off >>= 1) {
      if (t < off) red[t] += red[t + off];
      __syncthreads();
    }
    if (t == 0) logits[n] = red[0] + bc[n];
    __syncthreads();
  }
  if (t == 0) {
    float mx = logits[0];
    for (int n = 1; n < 10; ++n) mx = fmaxf(mx, logits[n]);
    float ex[10], sm = 0.f;
    for (int n = 0; n < 10; ++n) { ex[n] = expf(logits[n] - mx); sm += ex[n]; }
    const float inv = 1.f / sm;
    for (int n = 0; n < 10; ++n) {
      out[b*10 + n] = ex[n] * inv;          // X_predicted
      out[10240 + b*10 + n] = logits[n];    // X_classified
    }
  }
}

// ---------------------------------------------------------------- launch
extern "C" void kernel_launch(void* const* d_in, const int* in_sizes, int n_in,
                              void* d_out, int out_size, void* d_ws, size_t ws_size,
                              hipStream_t stream) {
  const float* Xin = (const float*)d_in[0];
  const float* hp  = (const float*)d_in[1];
  const float* W0  = (const float*)d_in[2];
  const float* Ws  = (const float*)d_in[3];
  const float* bs  = (const float*)d_in[4];
  const float* Wc  = (const float*)d_in[5];
  const float* bc  = (const float*)d_in[6];
  float* out = (float*)d_out;

  char* ws = (char*)d_ws;
  float* Xb = (float*)ws;                                   // 3072*1024 f32
  float* Yb = Xb + (size_t)NROWS * DD;                      // 3072*1024 f32
  __hip_bfloat16* stage =
      (__hip_bfloat16*)(ws + 2 * (size_t)NROWS * DD * 4);   // 17*3072*1024 bf16
  ushort* X0bf = (ushort*)(ws + 2 * (size_t)NROWS * DD * 4
                              + (size_t)NLAY * NROWS * DD * 2);   // 3072*1024 bf16
  ushort* Wbf  = X0bf + (size_t)NROWS * DD;                 // 17*1024*1024 bf16

  convw_kernel<<<17408, 256, 0, stream>>>(W0, Ws, Wbf);
  prep_kernel<<<NROWS, 256, 0, stream>>>(Xin, X0bf);

  // layer 0: Linear (no bias), then projection
  gemm_kernel<<<dim3(8, 24), 256, 0, stream>>>(X0bf, Wbf, Xb, bs, hp, Yb, 0);
  proj_kernel<<<768, 256, 0, stream>>>(Yb, Xb, stage, 0, 16);

  for (int l = 0; l < 16; ++l) {
    gemm_kernel<<<dim3(8, 24), 256, 0, stream>>>(
        (const ushort*)(stage + (size_t)l * NROWS * DD),
        Wbf + (size_t)(l + 1) * DD * DD,
        Xb, bs + (size_t)l * DD, hp, Yb, 1);
    proj_kernel<<<768, 256, 0, stream>>>(Yb, Xb, stage, l + 1, 12);
  }

  transpose_kernel<<<dim3(4, NROWS), 256, 0, stream>>>(stage, out + 20480);
  classify_kernel<<<1024, 256, 0, stream>>>(Xb, Wc, bc, out);
}